// Round 22
// baseline (60.080 us; speedup 1.0000x reference)
//
#include <hip/hip_runtime.h>
#include <math.h>

#define BATCH 32
#define NN 1024
#define FF 128
#define HH 128
#define NODES 32   // nodes per block in kernel A
#define PROW 72    // padded P-tile row (bf16): 144B, spreads banks

typedef __attribute__((ext_vector_type(8))) short short8v;   // 8 bf16
typedef __attribute__((ext_vector_type(4))) float f32x4;     // MFMA acc

__device__ __forceinline__ unsigned short f2bf(float f) {    // RNE f32->bf16
    unsigned u = __float_as_uint(f);
    u += 0x7fffu + ((u >> 16) & 1u);
    return (unsigned short)(u >> 16);
}

// ---------------- Kernel A: h = X@W -> g (MFMA-B-fragment-swizzled bf16);
// a_self / a_neigh scalars.  g[(batch,kc,ct,lane=kg*16+li,e)] = h[kc*32+kg*8+e][ct*16+li]
__global__ __launch_bounds__(128) void gat_hidden(
    const float* __restrict__ X,      // [B,N,F]
    const float* __restrict__ W,      // [F,H]
    const float* __restrict__ Wself,  // [H]
    const float* __restrict__ Wneigh, // [H]
    unsigned short* __restrict__ g,   // [B][32 kc][8 ct][64 lane][8] bf16
    float* __restrict__ a_self,       // [B*N]
    float* __restrict__ a_neigh)      // [B*N]
{
    __shared__ float xs[NODES][FF];      // 16 KB
    __shared__ float hs[NODES][HH + 1];  // 16.5 KB
    const int tid = threadIdx.x;
    const long base_node = (long)blockIdx.x * NODES;
    const int batch = (int)(base_node >> 10);
    const int kc = (int)((base_node & 1023) >> 5);   // 32-node chunk index

    const float4* X4 = (const float4*)(X + base_node * FF);
    float4* xs4 = (float4*)&xs[0][0];
#pragma unroll
    for (int k = 0; k < (NODES * FF) / (4 * 128); k++)
        xs4[k * 128 + tid] = X4[k * 128 + tid];
    __syncthreads();

    float acc[NODES];
#pragma unroll
    for (int n = 0; n < NODES; n++) acc[n] = 0.f;
    const int c = tid;
    for (int fq = 0; fq < FF / 4; fq++) {
        const float w0 = W[(4 * fq + 0) * HH + c];
        const float w1 = W[(4 * fq + 1) * HH + c];
        const float w2 = W[(4 * fq + 2) * HH + c];
        const float w3 = W[(4 * fq + 3) * HH + c];
#pragma unroll
        for (int n = 0; n < NODES; n++) {
            const float4 x4 = *(const float4*)&xs[n][4 * fq];
            acc[n] += x4.x * w0 + x4.y * w1 + x4.z * w2 + x4.w * w3;
        }
    }
    {
        const int ct = c >> 4, li = c & 15;
        unsigned short* gb = g + ((((size_t)batch * 32 + kc) * 8 + ct) * 64) * 8;
        union { uint4 q; unsigned short u[8]; } pk;
#pragma unroll
        for (int kg = 0; kg < 4; kg++) {
#pragma unroll
            for (int e = 0; e < 8; e++) pk.u[e] = f2bf(acc[kg * 8 + e]);
            *(uint4*)(gb + (kg * 16 + li) * 8) = pk.q;
        }
    }
#pragma unroll
    for (int n = 0; n < NODES; n++) hs[n][c] = acc[n];
    __syncthreads();

    if (tid < 2 * NODES) {
        const int n = tid & (NODES - 1);
        const float* wvp = (tid < NODES) ? Wself : Wneigh;
        float s = 0.f;
        for (int cc = 0; cc < HH; cc++) s += hs[n][cc] * wvp[cc];
        if (tid < NODES) a_self[base_node + n] = s;
        else             a_neigh[base_node + n] = s;
    }
}

// ---------------- Kernel B: fused P@H (R21 geometry) + counted-wait barriers.
// 64-row tiles, 8 waves, wave = one ct column x 4 row-tiles, full K.
// Sync = lgkmcnt(0) + raw s_barrier (NO vmcnt drain): global loads stay in
// flight across barriers. adj pipeline is 2 iters deep (reg sets A/B).
// B-loads issued first (oldest) so MFMA's counted vmcnt leaves adj in flight.
// Numerics identical to R19/R21: unnormalized exp, rowsum of bf16-ROUNDED p.
__global__ __launch_bounds__(512) void gat_attend(
    const float* __restrict__ adj,     // [B,N,N]
    const float* __restrict__ mask,    // [B,N]
    const unsigned short* __restrict__ g, // swizzled bf16 h
    const float* __restrict__ a_self,  // [B*N]
    const float* __restrict__ a_neigh, // [B*N]
    const float* __restrict__ bvec,    // [H]
    float* __restrict__ out)           // [B,N,H]
{
    const int tid = threadIdx.x;
    const int lane = tid & 63;
    const int wv = tid >> 6;                 // 0..7 = ct column
    // 512 blocks; XCD x owns 4 batches
    const int b = blockIdx.x;
    const int xcd = b & 7;
    const int rest = b >> 3;                 // 0..63
    const int batch = xcd * 4 + (rest >> 4);
    const int tile = rest & 15;              // 0..15 (64-row tiles)
    const int r0 = batch * NN + tile * 64;   // 768 % 64 == 0: tile uniform

    if (mask[r0] == 0.f) {                   // invalid tile: zero-fill out
        float4* o4 = (float4*)(out + (size_t)r0 * HH);
#pragma unroll
        for (int k = 0; k < 4; k++)
            o4[k * 512 + tid] = make_float4(0.f, 0.f, 0.f, 0.f);
        return;
    }

    __shared__ unsigned short P[2][64 * PROW];   // 18432 B
    __shared__ float rtot[64];                   // 256 B

    // staging: thread owns row srow (tid>>3), float4-cols c8 and c8+8
    const int srow = tid >> 3;               // 0..63
    const int c8 = tid & 7;
    const float4* arow = (const float4*)(adj + (size_t)(r0 + srow) * NN);
    const float4* anp = (const float4*)(a_neigh + (size_t)batch * NN);
    const float asl = a_self[r0 + srow];
    const unsigned short* gb = g + (size_t)batch * 131072;   // 32*8*64*8

    float rs = 0.f;

#define LOADS_TO(t, A0, A1, N0, N1)                   \
    {                                                 \
        const int o = (t) * 16 + c8;                  \
        A0 = arow[o];     A1 = arow[o + 8];           \
        N0 = anp[o];      N1 = anp[o + 8];            \
    }
#define EW(a4, n4, elem0, buf)                                                       \
    {                                                                                \
        union { unsigned short u[4]; uint2 q; } wq;                                  \
        float x, p;                                                                  \
        x = asl + n4.x; p = (a4.x > 0.f) ? __expf(fmaxf(x, 0.2f * x)) : 0.f;         \
        wq.u[0] = f2bf(p); rs += __uint_as_float((unsigned)wq.u[0] << 16);           \
        x = asl + n4.y; p = (a4.y > 0.f) ? __expf(fmaxf(x, 0.2f * x)) : 0.f;         \
        wq.u[1] = f2bf(p); rs += __uint_as_float((unsigned)wq.u[1] << 16);           \
        x = asl + n4.z; p = (a4.z > 0.f) ? __expf(fmaxf(x, 0.2f * x)) : 0.f;         \
        wq.u[2] = f2bf(p); rs += __uint_as_float((unsigned)wq.u[2] << 16);           \
        x = asl + n4.w; p = (a4.w > 0.f) ? __expf(fmaxf(x, 0.2f * x)) : 0.f;         \
        wq.u[3] = f2bf(p); rs += __uint_as_float((unsigned)wq.u[3] << 16);           \
        *(uint2*)&P[buf][srow * PROW + (elem0)] = wq.q;                              \
    }
#define EXPWRITE_FROM(buf, A0, A1, N0, N1)   \
    {                                        \
        EW(A0, N0, c8 * 4, buf)              \
        EW(A1, N1, 32 + c8 * 4, buf)         \
    }
    // LDS-visibility barrier WITHOUT vmcnt drain: global loads stay in flight.
#define SYNC()                                                  \
    {                                                           \
        asm volatile("s_waitcnt lgkmcnt(0)" ::: "memory");      \
        __builtin_amdgcn_s_barrier();                           \
    }

    f32x4 acc[4];                            // one per 16-row tile
#pragma unroll
    for (int rt = 0; rt < 4; rt++)
#pragma unroll
        for (int i = 0; i < 4; i++) acc[rt][i] = 0.f;

    const int li = lane & 15;
    const int kg8 = (lane >> 4) * 8;
    const float bv = bvec[wv * 16 + li];

    // adj pipeline registers: set a = adj(t+1) at iter t entry; set b = landing
    float4 Aa0, Aa1, Na0, Na1, Ab0, Ab1, Nb0, Nb1;

    // prologue: P[0] <- iter0 data; set a <- adj(1)
    LOADS_TO(0, Aa0, Aa1, Na0, Na1)
    EXPWRITE_FROM(0, Aa0, Aa1, Na0, Na1)
    LOADS_TO(1, Aa0, Aa1, Na0, Na1)
    SYNC()

    // iter body: t = iter index, cur = t&1; IN holds adj(t+1), OUT lands adj(t+2)
#define BODY(t, IA0, IA1, IN0, IN1, OA0, OA1, ON0, ON1)                               \
    {                                                                                 \
        const int cur = (t) & 1;                                                      \
        /* 1. B-loads for this iter (oldest outstanding) */                           \
        const short8v bf0 = *(const short8v*)(gb + ((size_t)(((t) * 2 + 0) * 8 + wv) * 64 + lane) * 8); \
        const short8v bf1 = *(const short8v*)(gb + ((size_t)(((t) * 2 + 1) * 8 + wv) * 64 + lane) * 8); \
        /* 2. adj prefetch 2 iters ahead (stays in flight across barrier) */          \
        if ((t) < 14) LOADS_TO((t) + 2, OA0, OA1, ON0, ON1)                           \
        /* 3. MFMA on P[cur] */                                                       \
        _Pragma("unroll")                                                             \
        for (int rt = 0; rt < 4; rt++) {                                              \
            const short8v af0 = *(const short8v*)&P[cur][(rt * 16 + li) * PROW + kg8];          \
            acc[rt] = __builtin_amdgcn_mfma_f32_16x16x32_bf16(af0, bf0, acc[rt], 0, 0, 0);      \
        }                                                                             \
        _Pragma("unroll")                                                             \
        for (int rt = 0; rt < 4; rt++) {                                              \
            const short8v af1 = *(const short8v*)&P[cur][(rt * 16 + li) * PROW + 32 + kg8];     \
            acc[rt] = __builtin_amdgcn_mfma_f32_16x16x32_bf16(af1, bf1, acc[rt], 0, 0, 0);      \
        }                                                                             \
        /* 4. stage iter t+1 from IN (issued a full iter ago) */                      \
        if ((t) < 15) EXPWRITE_FROM(cur ^ 1, IA0, IA1, IN0, IN1)                      \
        SYNC()                                                                        \
    }

    for (int i2 = 0; i2 < 8; ++i2) {
        const int t0 = 2 * i2;
        BODY(t0,     Aa0, Aa1, Na0, Na1, Ab0, Ab1, Nb0, Nb1)
        BODY(t0 + 1, Ab0, Ab1, Nb0, Nb1, Aa0, Aa1, Na0, Na1)
    }

    // rowsum: 8 threads per row (consecutive lanes) hold partials
    rs += __shfl_xor(rs, 1);
    rs += __shfl_xor(rs, 2);
    rs += __shfl_xor(rs, 4);
    if ((lane & 7) == 0) rtot[srow] = rs;
    __syncthreads();

    // epilogue: wave wv owns out-cols wv*16..+15 for all 64 rows
#pragma unroll
    for (int rt = 0; rt < 4; rt++) {
#pragma unroll
        for (int i = 0; i < 4; i++) {
            const int r = rt * 16 + (lane >> 4) * 4 + i;
            const float inv = 1.f / rtot[r];
            out[(size_t)(r0 + r) * HH + wv * 16 + li] = acc[rt][i] * inv + bv;
        }
    }
#undef LOADS_TO
#undef EW
#undef EXPWRITE_FROM
#undef SYNC
#undef BODY
}

extern "C" void kernel_launch(void* const* d_in, const int* in_sizes, int n_in,
                              void* d_out, int out_size, void* d_ws, size_t ws_size,
                              hipStream_t stream) {
    const float* X      = (const float*)d_in[0];  // M_features [B,N,F]
    const float* adj    = (const float*)d_in[1];  // M_adjacency [B,N,N]
    const float* mask   = (const float*)d_in[2];  // [B,N]
    const float* W      = (const float*)d_in[3];  // [F,H]
    const float* bvec   = (const float*)d_in[4];  // [H]
    const float* Wself  = (const float*)d_in[5];  // [H,1]
    const float* Wneigh = (const float*)d_in[6];  // [H,1]
    float* out = (float*)d_out;

    char* wsb = (char*)d_ws;
    unsigned short* g = (unsigned short*)wsb;                // 8 MB
    float* a_self  = (float*)(wsb + (size_t)BATCH * NN * HH * 2);
    float* a_neigh = a_self + (size_t)BATCH * NN;

    gat_hidden<<<(BATCH * NN) / NODES, 128, 0, stream>>>(
        X, W, Wself, Wneigh, g, a_self, a_neigh);
    gat_attend<<<512, 512, 0, stream>>>(
        adj, mask, g, a_self, a_neigh, bvec, out);
}